// Round 3
// baseline (2777.657 us; speedup 1.0000x reference)
//
#include <hip/hip_runtime.h>

// ---------------- problem constants ----------------
#define B_     8192
#define D_     32
#define H_     128
#define PH_    64
#define PREP_  10
#define CS_    8
#define CH_    32
#define NT_    16
#define NO_    4096
#define NPOST_ 4
#define DT_    0.1f
#define TWO_LOGC 1.8378770664093453f   // 2*log(sqrt(2*pi))

// ---------------- bf16 fragment-blob offsets (ushort elements) ----------------
// blob layout for a KxN weight: element ((kc*ntiles+nt)*64+lane)*8+j holds
// W[kc*32 + 4*((lane>>4)&3) + (j&3) + 16*(j>>2)][nt*16 + (lane&15)]
#define OFF_XZ   0        // 64x128
#define OFF_HZ   8192     // 128x128
#define OFF_XN   24576
#define OFF_HN   32768
#define OFF_PW1  49152    // 128x64
#define OFF_PW2  57344    // 64x64
#define OFF_WIHR 61440    // 320x128 per gate
#define OFF_WIHZ 102400
#define OFF_WIHN 143360
#define OFF_WHHR 184320   // 128x128 per gate
#define OFF_WHHZ 200704
#define OFF_WHHN 217088
#define BLOB_ELEMS 233472
#define INV_BYTE_OFF ((size_t)BLOB_ELEMS*2)

// activation LDS strides (ushorts): stride_dw % 32 == 4 -> ds_read_b128
// start-banks spread evenly (8 groups x 8 lanes = m134 conflict-free floor)
#define STRH 136
#define STRP 72
#define STRG 328
#define AOFF_HB   0
#define AOFF_PB   2176
#define AOFF_UN   3328          // union: zh(2176) / qb(1152) / gin(5248)
#define ACT_W     8576

// shared fp32 constant table offsets (floats)
#define SB_XZ    0
#define SB_XN    128
#define SB_P1    256
#define SB_P2    320
#define SB_BRZ   384      // b_ih+b_hh for r (0..127) and z (128..255)
#define SB_BIN   640      // b_ih n-chunk
#define SB_BHN   768      // b_hh n-chunk
#define SB_WPREP 896      // 1280
#define SB_BPREP 2176     // 320
#define SB_TOT   2496

typedef float f4  __attribute__((ext_vector_type(4)));
typedef short bf8 __attribute__((ext_vector_type(8)));

__device__ __forceinline__ f4 mfma16(bf8 a, bf8 b, f4 c){
  return __builtin_amdgcn_mfma_f32_16x16x32_bf16(a,b,c,0,0,0);
}
__device__ __forceinline__ unsigned short f2bf(float f){
  unsigned int u = __builtin_bit_cast(unsigned int, f);
  u = (u + 0x7FFFu + ((u>>16)&1u)) >> 16;
  return (unsigned short)u;
}
__device__ __forceinline__ float sigmoidf_(float x){ return 1.f/(1.f+__expf(-x)); }
// column k -> ushort position inside a swizzled activation row: fragment order
__device__ __forceinline__ int permk(int k){
  return ((k>>5)<<5) | (((k>>2)&3)<<3) | (((k>>4)&1)<<2) | (k&3);
}

// 16xK @ KxN GEMM; A from wave-private swizzled LDS (one b128/lane/kc),
// B fragments streamed directly from global (L2-resident blob).
template<int NKC,int NT>
__device__ __forceinline__ void gemmG(f4* acc, const unsigned short* Ald, int strideUsh,
                                      const unsigned short* __restrict__ Bg, int lane){
  const unsigned short* arow = Ald + (lane&15)*strideUsh + (lane>>4)*8;
  const unsigned short* bl   = Bg + lane*8;
  #pragma unroll
  for(int kc=0;kc<NKC;kc++){
    bf8 av = *(const bf8*)(arow + kc*32);
    #pragma unroll
    for(int nt=0;nt<NT;nt++){
      bf8 bv = *(const bf8*)(bl + (kc*NT+nt)*512);
      acc[nt] = mfma16(av, bv, acc[nt]);
    }
  }
}

template<int NT>
__device__ __forceinline__ void initacc(f4* acc, const float* b, int lc){
  #pragma unroll
  for(int nt=0;nt<NT;nt++){ float v = b[nt*16+lc]; f4 t = {v,v,v,v}; acc[nt]=t; }
}

// ---------------- prep kernels ----------------
__global__ void init_inv(unsigned short* inv, float* outLoss){
  int i = blockIdx.x*256 + threadIdx.x;
  if(i < NT_*B_) inv[i] = 0xFFFFu;
  if(i == 0) *outLoss = 0.f;
}

__global__ void scatter_inv(unsigned short* inv, const int* __restrict__ obs){
  int i = blockIdx.x*256 + threadIdx.x;
  if(i < NT_*NO_){
    int t = i >> 12;
    int o = i & 4095;
    inv[(size_t)t*B_ + obs[i]] = (unsigned short)o;
  }
}

__global__ void build_blobs(const float* __restrict__ pw1, const float* __restrict__ pw2,
                            const float* __restrict__ xzw, const float* __restrict__ hzw,
                            const float* __restrict__ xnw, const float* __restrict__ hnw,
                            const float* __restrict__ wih, const float* __restrict__ whh,
                            unsigned short* __restrict__ blob){
  int sec = blockIdx.y;
  int e = blockIdx.x*256 + threadIdx.x;
  const float* src; int Ksrc, N, ld, col0, off, cnt;
  switch(sec){
    case 0:  src=xzw; Ksrc=64;  N=128; ld=128; col0=0; off=OFF_XZ;  cnt=8192;  break;
    case 1:  src=hzw; Ksrc=128; N=128; ld=128; col0=0; off=OFF_HZ;  cnt=16384; break;
    case 2:  src=xnw; Ksrc=64;  N=128; ld=128; col0=0; off=OFF_XN;  cnt=8192;  break;
    case 3:  src=hnw; Ksrc=128; N=128; ld=128; col0=0; off=OFF_HN;  cnt=16384; break;
    case 4:  src=pw1; Ksrc=128; N=64;  ld=64;  col0=0; off=OFF_PW1; cnt=8192;  break;
    case 5:  src=pw2; Ksrc=64;  N=64;  ld=64;  col0=0; off=OFF_PW2; cnt=4096;  break;
    case 6: case 7: case 8: {
      int g = sec-6; src=wih; Ksrc=320; N=128; ld=384; col0=g*128;
      off=OFF_WIHR + g*40960; cnt=40960; } break;
    default: {
      int g = sec-9; src=whh; Ksrc=128; N=128; ld=384; col0=g*128;
      off=OFF_WHHR + g*16384; cnt=16384; } break;
  }
  if(e >= cnt) return;
  int ntiles = N >> 4;
  int perkc = ntiles << 9;
  int kc = e / perkc, rem = e % perkc;
  int nt = rem >> 9, li = rem & 511;
  int lane = li >> 3, j = li & 7;
  int n = nt*16 + (lane & 15);
  int k = kc*32 + ((lane>>4)&3)*4 + (j&3) + ((j>>2)<<4);
  float v = (k < Ksrc) ? src[(size_t)k*ld + col0 + n] : 0.f;
  blob[off + e] = f2bf(v);
}

// ---------------- fused persistent kernel: 2 independent waves/block ----------------
__global__ __launch_bounds__(128,1) void fused(
    const float* __restrict__ X, const float* __restrict__ M,
    const float* __restrict__ cov,
    const float* __restrict__ cm_w1, const float* __restrict__ cm_b1,
    const float* __restrict__ cm_w2, const float* __restrict__ cm_b2,
    const float* __restrict__ p_b1, const float* __restrict__ p_b2,
    const float* __restrict__ xz_b, const float* __restrict__ xn_b,
    const float* __restrict__ b_ih, const float* __restrict__ b_hh,
    const float* __restrict__ w_prep, const float* __restrict__ bias_prep,
    const unsigned short* __restrict__ blob, const unsigned short* __restrict__ inv,
    float* __restrict__ outH, float* __restrict__ outP, float* __restrict__ outLoss)
{
  __shared__ __align__(16) unsigned short act[2*ACT_W];
  __shared__ __align__(16) float rs[2][16*132];   // wave-private fp32 r staging
  __shared__ float sb[SB_TOT];
  __shared__ float hInit[32][132];
  __shared__ float c1s[32][36];

  const int tid  = threadIdx.x;
  const int lane = tid & 63;
  const int w    = tid >> 6;
  const int lc   = lane & 15;
  const int a4   = lane >> 4;          // 0..3
  const int base = blockIdx.x*32 + w*16;
  float lsum = 0.f;

  unsigned short* hb  = act + w*ACT_W + AOFF_HB;
  unsigned short* pb  = act + w*ACT_W + AOFF_PB;
  unsigned short* un  = act + w*ACT_W + AOFF_UN;   // zh / qb / gin
  float* rsc = &rs[w][0];

  // ---- stage fp32 constants ----
  for(int i=tid;i<128;i+=128){ sb[SB_XZ+i]=xz_b[i]; sb[SB_XN+i]=xn_b[i];
                               sb[SB_BIN+i]=b_ih[256+i]; sb[SB_BHN+i]=b_hh[256+i]; }
  for(int i=tid;i<64;i+=128){ sb[SB_P1+i]=p_b1[i]; sb[SB_P2+i]=p_b2[i]; }
  for(int i=tid;i<256;i+=128) sb[SB_BRZ+i]=b_ih[i]+b_hh[i];
  for(int i=tid;i<1280;i+=128) sb[SB_WPREP+i]=w_prep[i];
  for(int i=tid;i<320;i+=128) sb[SB_BPREP+i]=bias_prep[i];

  // ---- init h = tanh(relu(cov@cm_w1+b1)@cm_w2+b2) (one-time scalar path) ----
  {
    int row = tid>>2, q = tid&3;
    float a[8];
    #pragma unroll
    for(int j=0;j<8;j++) a[j]=cm_b1[q*8+j];
    #pragma unroll
    for(int k=0;k<CS_;k++){
      float cv = cov[(size_t)(blockIdx.x*32+row)*CS_+k];
      #pragma unroll
      for(int j=0;j<8;j++) a[j] += cv*cm_w1[k*CH_+q*8+j];
    }
    #pragma unroll
    for(int j=0;j<8;j++) c1s[row][q*8+j] = fmaxf(a[j],0.f);
    __syncthreads();
    float acc2[32];
    #pragma unroll
    for(int j=0;j<32;j++) acc2[j]=cm_b2[q*32+j];
    for(int k=0;k<CH_;k++){
      float cv = c1s[row][k];
      #pragma unroll
      for(int j=0;j<32;j++) acc2[j] += cv*cm_w2[k*H_+q*32+j];
    }
    #pragma unroll
    for(int j=0;j<32;j++) hInit[row][q*32+j] = tanhf(acc2[j]);
    __syncthreads();
  }

  f4 hFr[8], pFr[4];
  #pragma unroll
  for(int nt=0;nt<8;nt++)
    #pragma unroll
    for(int g=0;g<4;g++){
      float v = hInit[w*16 + a4*4+g][nt*16+lc];
      hFr[nt][g]=v;
      hb[(a4*4+g)*STRH + permk(nt*16+lc)] = f2bf(v);
    }

  // ---- p_model ----
  auto pmodel = [&](){
    f4 q[4]; initacc<4>(q, sb+SB_P1, lc);
    gemmG<4,4>(q, hb, STRH, blob+OFF_PW1, lane);
    #pragma unroll
    for(int nt=0;nt<4;nt++)
      #pragma unroll
      for(int g=0;g<4;g++)
        un[(a4*4+g)*STRP + permk(nt*16+lc)] = f2bf(fmaxf(q[nt][g],0.f));
    f4 p[4]; initacc<4>(p, sb+SB_P2, lc);
    gemmG<2,4>(p, un, STRP, blob+OFF_PW2, lane);
    #pragma unroll
    for(int nt=0;nt<4;nt++){
      pFr[nt]=p[nt];
      #pragma unroll
      for(int g=0;g<4;g++)
        pb[(a4*4+g)*STRP + permk(nt*16+lc)] = f2bf(p[nt][g]);
    }
  };

  // ---- euler step: peak live = z(32)+acc(32)+hFr(32)+pFr(16) ----
  auto euler = [&](){
    f4 acc[8]; initacc<8>(acc, sb+SB_XZ, lc);
    gemmG<2,8>(acc, pb, STRP, blob+OFF_XZ, lane);
    gemmG<4,8>(acc, hb, STRH, blob+OFF_HZ, lane);
    f4 zr[8];
    #pragma unroll
    for(int nt=0;nt<8;nt++)
      #pragma unroll
      for(int g=0;g<4;g++){
        float z = sigmoidf_(acc[nt][g]);
        zr[nt][g]=z;
        un[(a4*4+g)*STRH + permk(nt*16+lc)] = f2bf(z*hFr[nt][g]);   // zh
      }
    initacc<8>(acc, sb+SB_XN, lc);
    gemmG<2,8>(acc, pb, STRP, blob+OFF_XN, lane);
    gemmG<4,8>(acc, un, STRH, blob+OFF_HN, lane);
    #pragma unroll
    for(int nt=0;nt<8;nt++)
      #pragma unroll
      for(int g=0;g<4;g++){
        float nn = tanhf(acc[nt][g]);
        float ho = hFr[nt][g];
        float hv = ho + DT_*(1.f-zr[nt][g])*(nn-ho);
        hFr[nt][g]=hv;
        hb[(a4*4+g)*STRH + permk(nt*16+lc)] = f2bf(hv);
      }
  };

  // ---- Bayesian jump: r staged via LDS; n-gate uses transform-then-accumulate ----
  auto jump = [&](int t){
    int og[4];
    #pragma unroll
    for(int g=0;g<4;g++){
      unsigned short v = inv[(size_t)t*B_ + base + a4*4 + g];
      og[g] = (v==0xFFFFu)? -1 : (int)v;
    }
    #pragma unroll
    for(int g=0;g<4;g++){
      int row = a4*4+g;
      int o = og[g];
      #pragma unroll
      for(int half=0; half<2; half++){
        int d = half*16 + lc;
        float xa=0.f, ma=0.f;
        if(o>=0){
          const float* Xr = X + ((size_t)t*NO_+o)*D_;
          const float* Mr = M + ((size_t)t*NO_+o)*D_;
          xa = Xr[d]; ma = Mr[d];
        }
        float mean = pFr[half][g];     // col d     -> tile half
        float lv   = pFr[2+half][g];   // col 32+d  -> tile 2+half
        float sg = __expf(0.5f*lv);
        float er = (xa-mean)/sg;
        if(ma>0.f) lsum += 0.5f*(er*er + lv + TWO_LOGC);
        const float* wp = sb + SB_WPREP + d*4*PREP_;
        const float* bpv= sb + SB_BPREP + d*PREP_;
        #pragma unroll
        for(int pr=0;pr<PREP_;pr++){
          float s = xa*wp[pr] + mean*wp[PREP_+pr] + lv*wp[2*PREP_+pr] + er*wp[3*PREP_+pr] + bpv[pr];
          s = fmaxf(s,0.f);
          float sv = (ma>0.f)? s : 0.f;
          un[row*STRG + permk(d*PREP_+pr)] = f2bf(sv);   // gin
        }
      }
    }
    // r gate -> LDS (releases regs before next gemm)
    {
      f4 acc[8]; initacc<8>(acc, sb+SB_BRZ, lc);
      gemmG<10,8>(acc, un, STRG, blob+OFF_WIHR, lane);
      gemmG<4,8> (acc, hb, STRH, blob+OFF_WHHR, lane);
      #pragma unroll
      for(int nt=0;nt<8;nt++)
        #pragma unroll
        for(int g=0;g<4;g++)
          rsc[(a4*4+g)*132 + nt*16+lc] = sigmoidf_(acc[nt][g]);
    }
    // z gate -> regs
    f4 zz[8];
    {
      f4 acc[8]; initacc<8>(acc, sb+SB_BRZ+128, lc);
      gemmG<10,8>(acc, un, STRG, blob+OFF_WIHZ, lane);
      gemmG<4,8> (acc, hb, STRH, blob+OFF_WHHZ, lane);
      #pragma unroll
      for(int nt=0;nt<8;nt++)
        #pragma unroll
        for(int g=0;g<4;g++) zz[nt][g] = sigmoidf_(acc[nt][g]);
    }
    // n gate: gh first (init b_hh_n), transform acc = r*acc + b_ih_n, then add gi
    {
      f4 acc[8]; initacc<8>(acc, sb+SB_BHN, lc);
      gemmG<4,8>(acc, hb, STRH, blob+OFF_WHHN, lane);
      #pragma unroll
      for(int nt=0;nt<8;nt++)
        #pragma unroll
        for(int g=0;g<4;g++){
          float rv = rsc[(a4*4+g)*132 + nt*16+lc];
          acc[nt][g] = rv*acc[nt][g] + sb[SB_BIN + nt*16+lc];
        }
      gemmG<10,8>(acc, un, STRG, blob+OFF_WIHN, lane);
      #pragma unroll
      for(int nt=0;nt<8;nt++)
        #pragma unroll
        for(int g=0;g<4;g++){
          float nn = tanhf(acc[nt][g]);
          float z = zz[nt][g];
          float hv = (1.f-z)*nn + z*hFr[nt][g];
          if(og[g]>=0){
            hFr[nt][g]=hv;
            hb[(a4*4+g)*STRH + permk(nt*16+lc)] = f2bf(hv);
          }
        }
    }
  };

  // ---- sequence ----
  pmodel();
  for(int t=0;t<NT_;t++){
    euler();
    pmodel();
    jump(t);
    pmodel();
  }
  for(int it=0;it<NPOST_;it++){
    euler();
    pmodel();
  }

  // ---- outputs ----
  #pragma unroll
  for(int nt=0;nt<8;nt++)
    #pragma unroll
    for(int g=0;g<4;g++)
      outH[(size_t)(base + a4*4+g)*H_ + nt*16+lc] = hFr[nt][g];
  #pragma unroll
  for(int nt=0;nt<4;nt++)
    #pragma unroll
    for(int g=0;g<4;g++)
      outP[(size_t)(base + a4*4+g)*(2*D_) + nt*16+lc] = pFr[nt][g];

  #pragma unroll
  for(int off=32;off>0;off>>=1) lsum += __shfl_down(lsum, off);
  if(lane==0) atomicAdd(outLoss, lsum);
}

// ---------------- launcher ----------------
extern "C" void kernel_launch(void* const* d_in, const int* in_sizes, int n_in,
                              void* d_out, int out_size, void* d_ws, size_t ws_size,
                              hipStream_t stream){
  const float* X      = (const float*)d_in[0];
  const float* M      = (const float*)d_in[1];
  const int*   obs    = (const int*)  d_in[2];
  const float* cov    = (const float*)d_in[3];
  const float* cm_w1  = (const float*)d_in[4];
  const float* cm_b1  = (const float*)d_in[5];
  const float* cm_w2  = (const float*)d_in[6];
  const float* cm_b2  = (const float*)d_in[7];
  const float* p_w1   = (const float*)d_in[8];
  const float* p_b1   = (const float*)d_in[9];
  const float* p_w2   = (const float*)d_in[10];
  const float* p_b2   = (const float*)d_in[11];
  const float* xz_w   = (const float*)d_in[12];
  const float* xz_b   = (const float*)d_in[13];
  const float* hz_w   = (const float*)d_in[14];
  const float* xn_w   = (const float*)d_in[15];
  const float* xn_b   = (const float*)d_in[16];
  const float* hn_w   = (const float*)d_in[17];
  const float* w_ih   = (const float*)d_in[18];
  const float* w_hh   = (const float*)d_in[19];
  const float* b_ih   = (const float*)d_in[20];
  const float* b_hh   = (const float*)d_in[21];
  const float* w_prep = (const float*)d_in[22];
  const float* bprep  = (const float*)d_in[23];

  unsigned short* blob = (unsigned short*)d_ws;
  unsigned short* inv  = (unsigned short*)((char*)d_ws + INV_BYTE_OFF);
  float* outH = (float*)d_out;
  float* outP = outH + (size_t)B_*H_;
  float* outLoss = outP + (size_t)B_*2*D_;

  init_inv   <<<dim3((NT_*B_+255)/256), dim3(256), 0, stream>>>(inv, outLoss);
  scatter_inv<<<dim3((NT_*NO_+255)/256), dim3(256), 0, stream>>>(inv, obs);
  build_blobs<<<dim3(160,12), dim3(256), 0, stream>>>(p_w1,p_w2,xz_w,hz_w,xn_w,hn_w,w_ih,w_hh, blob);
  fused      <<<dim3(B_/32), dim3(128), 0, stream>>>(
      X, M, cov, cm_w1, cm_b1, cm_w2, cm_b2, p_b1, p_b2, xz_b, xn_b,
      b_ih, b_hh, w_prep, bprep, blob, inv, outH, outP, outLoss);
}

// Round 4
// 322.471 us; speedup vs baseline: 8.6137x; 8.6137x over previous
//
#include <hip/hip_runtime.h>

// ---------------- problem constants ----------------
#define B_     8192
#define D_     32
#define H_     128
#define PH_    64
#define PREP_  10
#define CS_    8
#define CH_    32
#define NT_    16
#define NO_    4096
#define NPOST_ 4
#define DT_    0.1f
#define TWO_LOGC 1.8378770664093453f   // 2*log(sqrt(2*pi))

// ---------------- bf16 fragment-blob offsets (ushort elements) ----------------
// blob layout for a KxN weight: element ((kc*ntiles+nt)*64+lane)*8+j holds
// W[kc*32 + 4*((lane>>4)&3) + (j&3) + 16*(j>>2)][nt*16 + (lane&15)]
#define OFF_XZ   0        // 64x128
#define OFF_HZ   8192     // 128x128
#define OFF_XN   24576
#define OFF_HN   32768
#define OFF_PW1  49152    // 128x64
#define OFF_PW2  57344    // 64x64
#define OFF_WIHR 61440    // 320x128 per gate
#define OFF_WIHZ 102400
#define OFF_WIHN 143360
#define OFF_WHHR 184320   // 128x128 per gate
#define OFF_WHHZ 200704
#define OFF_WHHN 217088
#define BLOB_ELEMS 233472
#define INV_BYTE_OFF ((size_t)BLOB_ELEMS*2)

// activation LDS strides (ushorts): stride_dw % 32 == 4 -> worst 2-way (free)
#define STRH 136
#define STRP 72
#define STRG 328
#define PFSTR 67          // fp32 p stride (floats)

// shared fp32 constant table offsets (floats)
#define SB_XZ    0
#define SB_XN    128
#define SB_P1    256
#define SB_P2    320
#define SB_BRZ   384      // b_ih+b_hh for r (0..127) and z (128..255)
#define SB_BIN   640      // b_ih n-chunk
#define SB_BHN   768      // b_hh n-chunk
#define SB_WPREP 896      // 1280
#define SB_BPREP 2176     // 320
#define SB_TOT   2496

typedef float f4  __attribute__((ext_vector_type(4)));
typedef short bf8 __attribute__((ext_vector_type(8)));

__device__ __forceinline__ f4 mfma16(bf8 a, bf8 b, f4 c){
  return __builtin_amdgcn_mfma_f32_16x16x32_bf16(a,b,c,0,0,0);
}
__device__ __forceinline__ unsigned short f2bf(float f){
  unsigned int u = __builtin_bit_cast(unsigned int, f);
  u = (u + 0x7FFFu + ((u>>16)&1u)) >> 16;
  return (unsigned short)u;
}
__device__ __forceinline__ float sigmoidf_(float x){ return 1.f/(1.f+__expf(-x)); }
// column k -> ushort position inside a swizzled activation row (fragment order)
__device__ __forceinline__ int permk(int k){
  return ((k>>5)<<5) | (((k>>2)&3)<<3) | (((k>>4)&1)<<2) | (k&3);
}

// 32-row x K x (NCT*16 cols) GEMM slice for wave w (N-split across 4 waves).
// A: block-shared swizzled LDS (one ds_read_b128 per row-tile per kc).
// B: fragment-ordered global blob (L2-resident), one b128 per tile.
// #pragma unroll 2 caps the in-flight load window (anti-spill: R2/R3 lesson).
template<int NKC,int NCT,int NT_TOT>
__device__ __forceinline__ void gemmB(f4 (&acc)[2][NCT], const unsigned short* Ald, int strideUsh,
                                      const unsigned short* __restrict__ Bg, int lane, int w){
  const int lc = lane & 15, a4 = lane >> 4;
  const unsigned short* a0 = Ald + lc*strideUsh + a4*8;
  const unsigned short* a1 = a0 + 16*strideUsh;
  const unsigned short* bl = Bg + (w*NCT)*512 + lane*8;
  #pragma unroll 2
  for(int kc=0;kc<NKC;kc++){
    bf8 av0 = *(const bf8*)(a0 + kc*32);
    bf8 av1 = *(const bf8*)(a1 + kc*32);
    #pragma unroll
    for(int ct=0;ct<NCT;ct++){
      bf8 bv = *(const bf8*)(bl + (size_t)(kc*NT_TOT+ct)*512);
      acc[0][ct] = mfma16(av0, bv, acc[0][ct]);
      acc[1][ct] = mfma16(av1, bv, acc[1][ct]);
    }
  }
}

// ---------------- prep kernels ----------------
__global__ void init_inv(unsigned short* inv, float* outLoss){
  int i = blockIdx.x*256 + threadIdx.x;
  if(i < NT_*B_) inv[i] = 0xFFFFu;
  if(i == 0) *outLoss = 0.f;
}

__global__ void scatter_inv(unsigned short* inv, const int* __restrict__ obs){
  int i = blockIdx.x*256 + threadIdx.x;
  if(i < NT_*NO_){
    int t = i >> 12;
    int o = i & 4095;
    inv[(size_t)t*B_ + obs[i]] = (unsigned short)o;
  }
}

__global__ void build_blobs(const float* __restrict__ pw1, const float* __restrict__ pw2,
                            const float* __restrict__ xzw, const float* __restrict__ hzw,
                            const float* __restrict__ xnw, const float* __restrict__ hnw,
                            const float* __restrict__ wih, const float* __restrict__ whh,
                            unsigned short* __restrict__ blob){
  int sec = blockIdx.y;
  int e = blockIdx.x*256 + threadIdx.x;
  const float* src; int Ksrc, N, ld, col0, off, cnt;
  switch(sec){
    case 0:  src=xzw; Ksrc=64;  N=128; ld=128; col0=0; off=OFF_XZ;  cnt=8192;  break;
    case 1:  src=hzw; Ksrc=128; N=128; ld=128; col0=0; off=OFF_HZ;  cnt=16384; break;
    case 2:  src=xnw; Ksrc=64;  N=128; ld=128; col0=0; off=OFF_XN;  cnt=8192;  break;
    case 3:  src=hnw; Ksrc=128; N=128; ld=128; col0=0; off=OFF_HN;  cnt=16384; break;
    case 4:  src=pw1; Ksrc=128; N=64;  ld=64;  col0=0; off=OFF_PW1; cnt=8192;  break;
    case 5:  src=pw2; Ksrc=64;  N=64;  ld=64;  col0=0; off=OFF_PW2; cnt=4096;  break;
    case 6: case 7: case 8: {
      int g = sec-6; src=wih; Ksrc=320; N=128; ld=384; col0=g*128;
      off=OFF_WIHR + g*40960; cnt=40960; } break;
    default: {
      int g = sec-9; src=whh; Ksrc=128; N=128; ld=384; col0=g*128;
      off=OFF_WHHR + g*16384; cnt=16384; } break;
  }
  if(e >= cnt) return;
  int ntiles = N >> 4;
  int perkc = ntiles << 9;
  int kc = e / perkc, rem = e % perkc;
  int nt = rem >> 9, li = rem & 511;
  int lane = li >> 3, j = li & 7;
  int n = nt*16 + (lane & 15);
  int k = kc*32 + ((lane>>4)&3)*4 + (j&3) + ((j>>2)<<4);
  float v = (k < Ksrc) ? src[(size_t)k*ld + col0 + n] : 0.f;
  blob[off + e] = f2bf(v);
}

// ---------------- fused persistent kernel ----------------
// 256 blocks x 256 threads; 32 rows/block; 4 waves N-split every GEMM.
__global__ __launch_bounds__(256,1) void fused(
    const float* __restrict__ X, const float* __restrict__ M,
    const float* __restrict__ cov,
    const float* __restrict__ cm_w1, const float* __restrict__ cm_b1,
    const float* __restrict__ cm_w2, const float* __restrict__ cm_b2,
    const float* __restrict__ p_b1, const float* __restrict__ p_b2,
    const float* __restrict__ xz_b, const float* __restrict__ xn_b,
    const float* __restrict__ b_ih, const float* __restrict__ b_hh,
    const float* __restrict__ w_prep, const float* __restrict__ bias_prep,
    const unsigned short* __restrict__ blob, const unsigned short* __restrict__ inv,
    float* __restrict__ outH, float* __restrict__ outP, float* __restrict__ outLoss)
{
  __shared__ __align__(16) unsigned short hb[32*STRH];   // bf16 h (swizzled)
  __shared__ __align__(16) unsigned short pb[32*STRP];   // bf16 p
  __shared__ __align__(16) unsigned short un[32*STRG];   // union: qb / zh / gin
  __shared__ __align__(16) float pf32[32*PFSTR];         // fp32 p
  __shared__ float sb[SB_TOT];
  __shared__ int obsO[32];
  __shared__ float lred[4];

  const int tid  = threadIdx.x;
  const int lane = tid & 63;
  const int w    = tid >> 6;           // wave 0..3
  const int lc   = lane & 15;
  const int a4   = lane >> 4;          // 0..3
  const int base = blockIdx.x * 32;
  float lsum = 0.f;

  // ---- stage fp32 constants ----
  for(int i=tid;i<128;i+=256){ sb[SB_XZ+i]=xz_b[i]; sb[SB_XN+i]=xn_b[i];
                               sb[SB_BIN+i]=b_ih[256+i]; sb[SB_BHN+i]=b_hh[256+i]; }
  for(int i=tid;i<64;i+=256){ sb[SB_P1+i]=p_b1[i]; sb[SB_P2+i]=p_b2[i]; }
  for(int i=tid;i<256;i+=256) sb[SB_BRZ+i]=b_ih[i]+b_hh[i];
  for(int i=tid;i<1280;i+=256) sb[SB_WPREP+i]=w_prep[i];
  for(int i=tid;i<320;i+=256) sb[SB_BPREP+i]=bias_prep[i];

  // ---- init h = tanh(relu(cov@cm_w1+b1)@cm_w2+b2) (one-time scalar path) ----
  {
    float* c1f = pf32;                  // [32][36] scratch
    float* hInitF = (float*)un;         // [32][132] scratch
    int row = tid>>3, q = tid&7;
    float a[4];
    #pragma unroll
    for(int j=0;j<4;j++) a[j]=cm_b1[q*4+j];
    #pragma unroll
    for(int k=0;k<CS_;k++){
      float cv = cov[(size_t)(base+row)*CS_+k];
      #pragma unroll
      for(int j=0;j<4;j++) a[j] += cv*cm_w1[k*CH_+q*4+j];
    }
    #pragma unroll
    for(int j=0;j<4;j++) c1f[row*36+q*4+j] = fmaxf(a[j],0.f);
    __syncthreads();
    float acc2[16];
    #pragma unroll
    for(int j=0;j<16;j++) acc2[j]=cm_b2[q*16+j];
    for(int k=0;k<CH_;k++){
      float cv = c1f[row*36+k];
      #pragma unroll
      for(int j=0;j<16;j++) acc2[j] += cv*cm_w2[k*H_+q*16+j];
    }
    #pragma unroll
    for(int j=0;j<16;j++) hInitF[row*132+q*16+j] = tanhf(acc2[j]);
    __syncthreads();
  }

  f4 hFr[2][2], pFr[2];
  {
    float* hInitF = (float*)un;
    #pragma unroll
    for(int rt=0;rt<2;rt++)
      #pragma unroll
      for(int ct=0;ct<2;ct++)
        #pragma unroll
        for(int g=0;g<4;g++){
          int row = rt*16 + a4*4+g, col = (2*w+ct)*16+lc;
          float v = hInitF[row*132+col];
          hFr[rt][ct][g]=v;
        }
    __syncthreads();                    // all reads of hInitF done before hb overwrite path
    #pragma unroll
    for(int rt=0;rt<2;rt++)
      #pragma unroll
      for(int ct=0;ct<2;ct++)
        #pragma unroll
        for(int g=0;g<4;g++){
          int row = rt*16 + a4*4+g, col = (2*w+ct)*16+lc;
          hb[row*STRH + permk(col)] = f2bf(hFr[rt][ct][g]);
        }
    __syncthreads();
  }

  // ---- p_model: wave w owns cols [16w,16w+16) of q and p ----
  auto pmodel = [&](){
    f4 acc[2][1];
    { float bv = sb[SB_P1 + w*16+lc]; f4 t={bv,bv,bv,bv}; acc[0][0]=t; acc[1][0]=t; }
    gemmB<4,1,4>(acc, hb, STRH, blob+OFF_PW1, lane, w);
    #pragma unroll
    for(int rt=0;rt<2;rt++)
      #pragma unroll
      for(int g=0;g<4;g++)
        un[(rt*16+a4*4+g)*STRP + permk(w*16+lc)] = f2bf(fmaxf(acc[rt][0][g],0.f));
    __syncthreads();
    { float bv = sb[SB_P2 + w*16+lc]; f4 t={bv,bv,bv,bv}; acc[0][0]=t; acc[1][0]=t; }
    gemmB<2,1,4>(acc, un, STRP, blob+OFF_PW2, lane, w);
    pFr[0]=acc[0][0]; pFr[1]=acc[1][0];
    #pragma unroll
    for(int rt=0;rt<2;rt++)
      #pragma unroll
      for(int g=0;g<4;g++){
        int row = rt*16+a4*4+g, col = w*16+lc;
        float v = acc[rt][0][g];
        pb[row*STRP + permk(col)] = f2bf(v);
        pf32[row*PFSTR + col] = v;
      }
    __syncthreads();
  };

  // ---- euler: h += DT*(1-z)*(n-h); wave w owns h cols [32w,32w+32) ----
  auto euler = [&](){
    f4 acc[2][2], zr[2][2];
    #pragma unroll
    for(int ct=0;ct<2;ct++){ float bv = sb[SB_XZ+(2*w+ct)*16+lc]; f4 t={bv,bv,bv,bv}; acc[0][ct]=t; acc[1][ct]=t; }
    gemmB<2,2,8>(acc, pb, STRP, blob+OFF_XZ, lane, w);
    gemmB<4,2,8>(acc, hb, STRH, blob+OFF_HZ, lane, w);
    #pragma unroll
    for(int rt=0;rt<2;rt++)
      #pragma unroll
      for(int ct=0;ct<2;ct++)
        #pragma unroll
        for(int g=0;g<4;g++){
          float z = sigmoidf_(acc[rt][ct][g]);
          zr[rt][ct][g]=z;
          int row = rt*16+a4*4+g, col = (2*w+ct)*16+lc;
          un[row*STRH + permk(col)] = f2bf(z*hFr[rt][ct][g]);   // zh
        }
    __syncthreads();
    #pragma unroll
    for(int ct=0;ct<2;ct++){ float bv = sb[SB_XN+(2*w+ct)*16+lc]; f4 t={bv,bv,bv,bv}; acc[0][ct]=t; acc[1][ct]=t; }
    gemmB<2,2,8>(acc, pb, STRP, blob+OFF_XN, lane, w);
    gemmB<4,2,8>(acc, un, STRH, blob+OFF_HN, lane, w);
    #pragma unroll
    for(int rt=0;rt<2;rt++)
      #pragma unroll
      for(int ct=0;ct<2;ct++)
        #pragma unroll
        for(int g=0;g<4;g++){
          float nn = tanhf(acc[rt][ct][g]);
          float ho = hFr[rt][ct][g];
          float hv = ho + DT_*(1.f-zr[rt][ct][g])*(nn-ho);
          hFr[rt][ct][g]=hv;
          int row = rt*16+a4*4+g, col = (2*w+ct)*16+lc;
          hb[row*STRH + permk(col)] = f2bf(hv);
        }
    __syncthreads();
  };

  // ---- Bayesian jump ----
  auto jump = [&](int t){
    if(tid < 32){
      unsigned short v = inv[(size_t)t*B_ + base + tid];
      obsO[tid] = (v == 0xFFFFu) ? -1 : (int)v;
    }
    __syncthreads();
    { // gin + loss: thread -> (row = tid>>3, d in [4q,4q+4))
      int row = tid>>3, q = tid&7, d0 = q*4;
      int o = obsO[row];
      float xa[4]={0.f,0.f,0.f,0.f}, ma[4]={0.f,0.f,0.f,0.f};
      if(o>=0){
        const float4 xv = *(const float4*)(X + ((size_t)t*NO_+o)*D_ + d0);
        const float4 mv = *(const float4*)(M + ((size_t)t*NO_+o)*D_ + d0);
        xa[0]=xv.x; xa[1]=xv.y; xa[2]=xv.z; xa[3]=xv.w;
        ma[0]=mv.x; ma[1]=mv.y; ma[2]=mv.z; ma[3]=mv.w;
      }
      #pragma unroll
      for(int j=0;j<4;j++){
        int d = d0+j;
        float mean = pf32[row*PFSTR + d];
        float lv   = pf32[row*PFSTR + D_ + d];
        float sg = __expf(0.5f*lv);
        float er = (xa[j]-mean)/sg;
        if(ma[j]>0.f) lsum += 0.5f*(er*er + lv + TWO_LOGC);
        const float* wp  = sb + SB_WPREP + d*4*PREP_;
        const float* bpv = sb + SB_BPREP + d*PREP_;
        #pragma unroll
        for(int pr=0;pr<PREP_;pr++){
          float s = xa[j]*wp[pr] + mean*wp[PREP_+pr] + lv*wp[2*PREP_+pr] + er*wp[3*PREP_+pr] + bpv[pr];
          s = fmaxf(s,0.f);
          un[row*STRG + permk(d*PREP_+pr)] = f2bf((ma[j]>0.f)? s : 0.f);  // gin
        }
      }
    }
    __syncthreads();
    f4 rv[2][2], zz[2][2], acc[2][2];
    // r gate
    #pragma unroll
    for(int ct=0;ct<2;ct++){ float bv = sb[SB_BRZ+(2*w+ct)*16+lc]; f4 t={bv,bv,bv,bv}; acc[0][ct]=t; acc[1][ct]=t; }
    gemmB<10,2,8>(acc, un, STRG, blob+OFF_WIHR, lane, w);
    gemmB<4,2,8> (acc, hb, STRH, blob+OFF_WHHR, lane, w);
    #pragma unroll
    for(int rt=0;rt<2;rt++)
      #pragma unroll
      for(int ct=0;ct<2;ct++)
        #pragma unroll
        for(int g=0;g<4;g++) rv[rt][ct][g] = sigmoidf_(acc[rt][ct][g]);
    // z gate
    #pragma unroll
    for(int ct=0;ct<2;ct++){ float bv = sb[SB_BRZ+128+(2*w+ct)*16+lc]; f4 t={bv,bv,bv,bv}; acc[0][ct]=t; acc[1][ct]=t; }
    gemmB<10,2,8>(acc, un, STRG, blob+OFF_WIHZ, lane, w);
    gemmB<4,2,8> (acc, hb, STRH, blob+OFF_WHHZ, lane, w);
    #pragma unroll
    for(int rt=0;rt<2;rt++)
      #pragma unroll
      for(int ct=0;ct<2;ct++)
        #pragma unroll
        for(int g=0;g<4;g++) zz[rt][ct][g] = sigmoidf_(acc[rt][ct][g]);
    // n gate: gh = h@whh_n first, transform acc = r*acc + b_ih_n, then += gin@wih_n
    #pragma unroll
    for(int ct=0;ct<2;ct++){ float bv = sb[SB_BHN+(2*w+ct)*16+lc]; f4 t={bv,bv,bv,bv}; acc[0][ct]=t; acc[1][ct]=t; }
    gemmB<4,2,8>(acc, hb, STRH, blob+OFF_WHHN, lane, w);
    #pragma unroll
    for(int rt=0;rt<2;rt++)
      #pragma unroll
      for(int ct=0;ct<2;ct++)
        #pragma unroll
        for(int g=0;g<4;g++)
          acc[rt][ct][g] = rv[rt][ct][g]*acc[rt][ct][g] + sb[SB_BIN+(2*w+ct)*16+lc];
    gemmB<10,2,8>(acc, un, STRG, blob+OFF_WIHN, lane, w);
    __syncthreads();   // all waves done reading hb before conditional hb writes
    #pragma unroll
    for(int rt=0;rt<2;rt++)
      #pragma unroll
      for(int ct=0;ct<2;ct++)
        #pragma unroll
        for(int g=0;g<4;g++){
          int row = rt*16+a4*4+g;
          float nn = tanhf(acc[rt][ct][g]);
          float z = zz[rt][ct][g];
          float hv = (1.f-z)*nn + z*hFr[rt][ct][g];
          if(obsO[row]>=0){
            hFr[rt][ct][g]=hv;
            hb[row*STRH + permk((2*w+ct)*16+lc)] = f2bf(hv);
          }
        }
    __syncthreads();
  };

  // ---- sequence ----
  pmodel();
  for(int t=0;t<NT_;t++){
    euler();
    pmodel();
    jump(t);
    pmodel();
  }
  for(int it=0;it<NPOST_;it++){
    euler();
    pmodel();
  }

  // ---- outputs ----
  #pragma unroll
  for(int rt=0;rt<2;rt++)
    #pragma unroll
    for(int ct=0;ct<2;ct++)
      #pragma unroll
      for(int g=0;g<4;g++)
        outH[(size_t)(base + rt*16+a4*4+g)*H_ + (2*w+ct)*16+lc] = hFr[rt][ct][g];
  #pragma unroll
  for(int rt=0;rt<2;rt++)
    #pragma unroll
    for(int g=0;g<4;g++)
      outP[(size_t)(base + rt*16+a4*4+g)*(2*D_) + w*16+lc] = pFr[rt][g];

  #pragma unroll
  for(int off=32;off>0;off>>=1) lsum += __shfl_down(lsum, off);
  if(lane==0) lred[w]=lsum;
  __syncthreads();
  if(tid==0) atomicAdd(outLoss, lred[0]+lred[1]+lred[2]+lred[3]);
}

// ---------------- launcher ----------------
extern "C" void kernel_launch(void* const* d_in, const int* in_sizes, int n_in,
                              void* d_out, int out_size, void* d_ws, size_t ws_size,
                              hipStream_t stream){
  const float* X      = (const float*)d_in[0];
  const float* M      = (const float*)d_in[1];
  const int*   obs    = (const int*)  d_in[2];
  const float* cov    = (const float*)d_in[3];
  const float* cm_w1  = (const float*)d_in[4];
  const float* cm_b1  = (const float*)d_in[5];
  const float* cm_w2  = (const float*)d_in[6];
  const float* cm_b2  = (const float*)d_in[7];
  const float* p_w1   = (const float*)d_in[8];
  const float* p_b1   = (const float*)d_in[9];
  const float* p_w2   = (const float*)d_in[10];
  const float* p_b2   = (const float*)d_in[11];
  const float* xz_w   = (const float*)d_in[12];
  const float* xz_b   = (const float*)d_in[13];
  const float* hz_w   = (const float*)d_in[14];
  const float* xn_w   = (const float*)d_in[15];
  const float* xn_b   = (const float*)d_in[16];
  const float* hn_w   = (const float*)d_in[17];
  const float* w_ih   = (const float*)d_in[18];
  const float* w_hh   = (const float*)d_in[19];
  const float* b_ih   = (const float*)d_in[20];
  const float* b_hh   = (const float*)d_in[21];
  const float* w_prep = (const float*)d_in[22];
  const float* bprep  = (const float*)d_in[23];

  unsigned short* blob = (unsigned short*)d_ws;
  unsigned short* inv  = (unsigned short*)((char*)d_ws + INV_BYTE_OFF);
  float* outH = (float*)d_out;
  float* outP = outH + (size_t)B_*H_;
  float* outLoss = outP + (size_t)B_*2*D_;

  init_inv   <<<dim3((NT_*B_+255)/256), dim3(256), 0, stream>>>(inv, outLoss);
  scatter_inv<<<dim3((NT_*NO_+255)/256), dim3(256), 0, stream>>>(inv, obs);
  build_blobs<<<dim3(160,12), dim3(256), 0, stream>>>(p_w1,p_w2,xz_w,hz_w,xn_w,hn_w,w_ih,w_hh, blob);
  fused      <<<dim3(B_/32), dim3(256), 0, stream>>>(
      X, M, cov, cm_w1, cm_b1, cm_w2, cm_b2, p_b1, p_b2, xz_b, xn_b,
      b_ih, b_hh, w_prep, bprep, blob, inv, outH, outP, outLoss);
}

// Round 5
// 229.585 us; speedup vs baseline: 12.0986x; 1.4046x over previous
//
#include <hip/hip_runtime.h>

// ---------------- problem constants ----------------
#define B_     8192
#define D_     32
#define H_     128
#define PH_    64
#define PREP_  10
#define CS_    8
#define CH_    32
#define NT_    16
#define NO_    4096
#define NPOST_ 4
#define DT_    0.1f
#define TWO_LOGC 1.8378770664093453f   // 2*log(sqrt(2*pi))

// ---------------- bf16 fragment-blob offsets (ushort elements) ----------------
// blob layout for a KxN weight: element ((kc*ntiles+nt)*64+lane)*8+j holds
// W[kc*32 + 4*((lane>>4)&3) + (j&3) + 16*(j>>2)][nt*16 + (lane&15)]
// Merged matrices: XZXN = [xz_w | xn_w] (64x256), WIH = full w_ih (320x384),
// WHH = full w_hh (128x384)  -> gate g's col c lives at tile 8g + c/16.
#define OFF_XZXN 0        // 64x256   -> 16384
#define OFF_HZ   16384    // 128x128  -> 16384
#define OFF_HN   32768    // 128x128  -> 16384
#define OFF_PW1  49152    // 128x64   -> 8192
#define OFF_PW2  57344    // 64x64    -> 4096
#define OFF_WIH  61440    // 320x384  -> 122880
#define OFF_WHH  184320   // 128x384  -> 49152
#define BLOB_ELEMS 233472
#define INV_BYTE_OFF ((size_t)BLOB_ELEMS*2)

// activation LDS strides (ushorts): stride_dw % 32 == 4 -> worst 2-way (free)
#define STRH 136
#define STRP 72
#define STRG 328
#define PFSTR 67          // fp32 p stride (floats)

// shared fp32 constant table offsets (floats)
#define SB_XZ    0
#define SB_XN    128
#define SB_P1    256
#define SB_P2    320
#define SB_BRZ   384      // b_ih+b_hh for r (0..127) and z (128..255)
#define SB_BIN   640      // b_ih n-chunk
#define SB_BHN   768      // b_hh n-chunk
#define SB_WPREP 896      // 1280
#define SB_BPREP 2176     // 320
#define SB_TOT   2496

typedef float f4  __attribute__((ext_vector_type(4)));
typedef short bf8 __attribute__((ext_vector_type(8)));

__device__ __forceinline__ f4 mfma16(bf8 a, bf8 b, f4 c){
  return __builtin_amdgcn_mfma_f32_16x16x32_bf16(a,b,c,0,0,0);
}
__device__ __forceinline__ unsigned short f2bf(float f){
  unsigned int u = __builtin_bit_cast(unsigned int, f);
  u = (u + 0x7FFFu + ((u>>16)&1u)) >> 16;
  return (unsigned short)u;
}
__device__ __forceinline__ float sigmoidf_(float x){ return 1.f/(1.f+__expf(-x)); }
// column k -> ushort position inside a swizzled activation row (fragment order)
__device__ __forceinline__ int permk(int k){
  return ((k>>5)<<5) | (((k>>2)&3)<<3) | (((k>>4)&1)<<2) | (k&3);
}

// Wave-sliced GEMM: rows = NRT*16, wave owns col tiles {tile0 + s*8 : s<NSEL}
// of an NTT-tile-wide fragment blob. A from swizzled LDS (1 ds_read_b128 per
// row-tile per kc), B streamed from L2-resident global blob.
// unroll 2 caps the in-flight load window (anti-spill; R2/R3 lesson).
template<int NKC,int NSEL,int NTT,int NRT>
__device__ __forceinline__ void gemmW(f4 (&acc)[NRT][NSEL], const unsigned short* Ald,
                                      int strideUsh, const unsigned short* __restrict__ Bg,
                                      int lane, int tile0){
  const int lc = lane & 15, a4 = lane >> 4;
  const unsigned short* a0 = Ald + lc*strideUsh + a4*8;
  const unsigned short* bl = Bg + (size_t)tile0*512 + lane*8;
  #pragma unroll 2
  for(int kc=0;kc<NKC;kc++){
    bf8 av0 = *(const bf8*)(a0 + kc*32);
    bf8 av1;
    if constexpr(NRT==2) av1 = *(const bf8*)(a0 + 16*strideUsh + kc*32);
    #pragma unroll
    for(int s=0;s<NSEL;s++){
      bf8 bv = *(const bf8*)(bl + (size_t)(kc*NTT + s*8)*512);
      acc[0][s] = mfma16(av0, bv, acc[0][s]);
      if constexpr(NRT==2) acc[1][s] = mfma16(av1, bv, acc[1][s]);
    }
  }
}

// ---------------- prep kernels ----------------
__global__ void init_inv(unsigned short* inv, float* outLoss){
  int i = blockIdx.x*256 + threadIdx.x;
  if(i < NT_*B_) inv[i] = 0xFFFFu;
  if(i == 0) *outLoss = 0.f;
}

__global__ void scatter_inv(unsigned short* inv, const int* __restrict__ obs){
  int i = blockIdx.x*256 + threadIdx.x;
  if(i < NT_*NO_){
    int t = i >> 12;
    int o = i & 4095;
    inv[(size_t)t*B_ + obs[i]] = (unsigned short)o;
  }
}

__global__ void build_blobs(const float* __restrict__ pw1, const float* __restrict__ pw2,
                            const float* __restrict__ xzw, const float* __restrict__ xnw,
                            const float* __restrict__ hzw, const float* __restrict__ hnw,
                            const float* __restrict__ wih, const float* __restrict__ whh,
                            unsigned short* __restrict__ blob){
  int sec = blockIdx.y;
  int e = blockIdx.x*256 + threadIdx.x;
  const float* src=nullptr; int N, ld, off, cnt;
  switch(sec){
    case 0: src=nullptr; N=256; ld=0;   off=OFF_XZXN; cnt=16384;  break; // [xz|xn]
    case 1: src=hzw;  N=128; ld=128; off=OFF_HZ;   cnt=16384;  break;
    case 2: src=hnw;  N=128; ld=128; off=OFF_HN;   cnt=16384;  break;
    case 3: src=pw1;  N=64;  ld=64;  off=OFF_PW1;  cnt=8192;   break;
    case 4: src=pw2;  N=64;  ld=64;  off=OFF_PW2;  cnt=4096;   break;
    case 5: src=wih;  N=384; ld=384; off=OFF_WIH;  cnt=122880; break;
    default:src=whh;  N=384; ld=384; off=OFF_WHH;  cnt=49152;  break;
  }
  if(e >= cnt) return;
  int ntiles = N >> 4;
  int perkc = ntiles << 9;
  int kc = e / perkc, rem = e % perkc;
  int nt = rem >> 9, li = rem & 511;
  int lane = li >> 3, j = li & 7;
  int n = nt*16 + (lane & 15);
  int k = kc*32 + ((lane>>4)&3)*4 + (j&3) + ((j>>2)<<4);
  float v;
  if(sec==0) v = (n<128) ? xzw[(size_t)k*128+n] : xnw[(size_t)k*128 + (n-128)];
  else       v = src[(size_t)k*ld + n];
  blob[off + e] = f2bf(v);
}

// ---------------- fused persistent kernel ----------------
// 256 blocks x 512 threads (8 waves = 2 waves/SIMD); 32 rows/block.
// Wave w owns h-col slice [16w,16w+16) of every 128/384-wide GEMM.
__global__ __launch_bounds__(512,2) void fused(
    const float* __restrict__ X, const float* __restrict__ M,
    const float* __restrict__ cov,
    const float* __restrict__ cm_w1, const float* __restrict__ cm_b1,
    const float* __restrict__ cm_w2, const float* __restrict__ cm_b2,
    const float* __restrict__ p_b1, const float* __restrict__ p_b2,
    const float* __restrict__ xz_b, const float* __restrict__ xn_b,
    const float* __restrict__ b_ih, const float* __restrict__ b_hh,
    const float* __restrict__ w_prep, const float* __restrict__ bias_prep,
    const unsigned short* __restrict__ blob, const unsigned short* __restrict__ inv,
    float* __restrict__ outH, float* __restrict__ outP, float* __restrict__ outLoss)
{
  __shared__ __align__(16) unsigned short hb[32*STRH];   // bf16 h (swizzled)
  __shared__ __align__(16) unsigned short pb[32*STRP];   // bf16 p
  __shared__ __align__(16) unsigned short un[32*STRG];   // union: qb / zh / gin
  __shared__ __align__(16) float pf32[32*PFSTR];         // fp32 p
  __shared__ float sb[SB_TOT];
  __shared__ int obsO[32];
  __shared__ float lred[8];

  const int tid  = threadIdx.x;
  const int lane = tid & 63;
  const int w    = tid >> 6;           // wave 0..7
  const int lc   = lane & 15;
  const int a4   = lane >> 4;          // 0..3
  const int base = blockIdx.x * 32;
  float lsum = 0.f;

  // ---- stage fp32 constants ----
  for(int i=tid;i<128;i+=512){ sb[SB_XZ+i]=xz_b[i]; sb[SB_XN+i]=xn_b[i];
                               sb[SB_BIN+i]=b_ih[256+i]; sb[SB_BHN+i]=b_hh[256+i]; }
  for(int i=tid;i<64;i+=512){ sb[SB_P1+i]=p_b1[i]; sb[SB_P2+i]=p_b2[i]; }
  for(int i=tid;i<256;i+=512) sb[SB_BRZ+i]=b_ih[i]+b_hh[i];
  for(int i=tid;i<1280;i+=512) sb[SB_WPREP+i]=w_prep[i];
  for(int i=tid;i<320;i+=512) sb[SB_BPREP+i]=bias_prep[i];

  // ---- init h = tanh(relu(cov@cm_w1+b1)@cm_w2+b2) (one-time scalar path) ----
  {
    float* c1f = pf32;                  // [32][36] scratch
    float* hInitF = (float*)un;         // [32][132] scratch
    int row = tid>>4, q = tid&15;
    float a[2];
    #pragma unroll
    for(int j=0;j<2;j++) a[j]=cm_b1[q*2+j];
    #pragma unroll
    for(int k=0;k<CS_;k++){
      float cv = cov[(size_t)(base+row)*CS_+k];
      #pragma unroll
      for(int j=0;j<2;j++) a[j] += cv*cm_w1[k*CH_+q*2+j];
    }
    #pragma unroll
    for(int j=0;j<2;j++) c1f[row*36+q*2+j] = fmaxf(a[j],0.f);
    __syncthreads();
    float acc2[8];
    #pragma unroll
    for(int j=0;j<8;j++) acc2[j]=cm_b2[q*8+j];
    for(int k=0;k<CH_;k++){
      float cv = c1f[row*36+k];
      #pragma unroll
      for(int j=0;j<8;j++) acc2[j] += cv*cm_w2[k*H_+q*8+j];
    }
    #pragma unroll
    for(int j=0;j<8;j++) hInitF[row*132+q*8+j] = tanhf(acc2[j]);
    __syncthreads();
  }

  f4 hFr[2];        // h cols [16w,16w+16), rows rt*16+a4*4+g
  f4 pFr;           // p rows (w&1)*16+a4*4+g, cols (w>>2? no:) see pmodel
  {
    float* hInitF = (float*)un;
    #pragma unroll
    for(int rt=0;rt<2;rt++)
      #pragma unroll
      for(int g=0;g<4;g++)
        hFr[rt][g] = hInitF[(rt*16+a4*4+g)*132 + w*16+lc];
    __syncthreads();                    // reads done before un reuse / hb write
    #pragma unroll
    for(int rt=0;rt<2;rt++)
      #pragma unroll
      for(int g=0;g<4;g++)
        hb[(rt*16+a4*4+g)*STRH + permk(w*16+lc)] = f2bf(hFr[rt][g]);
    __syncthreads();
  }

  const int prt = w & 1, pct = w >> 1;   // pmodel row/col split (8 waves on 32x64)

  // ---- p_model: wave w -> rows [16*prt), cols [16*pct) ----
  auto pmodel = [&](){
    f4 acc[1][1];
    { float bv = sb[SB_P1 + pct*16+lc]; f4 t={bv,bv,bv,bv}; acc[0][0]=t; }
    gemmW<4,1,4,1>(acc, hb + prt*16*STRH, STRH, blob+OFF_PW1, lane, pct);
    #pragma unroll
    for(int g=0;g<4;g++)
      un[(prt*16+a4*4+g)*STRP + permk(pct*16+lc)] = f2bf(fmaxf(acc[0][0][g],0.f));
    __syncthreads();
    { float bv = sb[SB_P2 + pct*16+lc]; f4 t={bv,bv,bv,bv}; acc[0][0]=t; }
    gemmW<2,1,4,1>(acc, un + prt*16*STRP, STRP, blob+OFF_PW2, lane, pct);
    pFr = acc[0][0];
    #pragma unroll
    for(int g=0;g<4;g++){
      int row = prt*16+a4*4+g, col = pct*16+lc;
      float v = acc[0][0][g];
      pb[row*STRP + permk(col)] = f2bf(v);
      pf32[row*PFSTR + col] = v;
    }
    __syncthreads();
  };

  // ---- euler: h += DT*(1-z)*(n-h); wave w owns h cols [16w,16w+16) ----
  auto euler = [&](){
    f4 ax[2][2];   // [rt][0]=xz part, [rt][1]=xn part (merged 256-wide blob)
    #pragma unroll
    for(int rt=0;rt<2;rt++){
      float bz = sb[SB_XZ + w*16+lc], bn = sb[SB_XN + w*16+lc];
      f4 tz={bz,bz,bz,bz}, tn={bn,bn,bn,bn};
      ax[rt][0]=tz; ax[rt][1]=tn;
    }
    gemmW<2,2,16,2>(ax, pb, STRP, blob+OFF_XZXN, lane, w);
    f4 ah[2][1]; { f4 z4={0.f,0.f,0.f,0.f}; ah[0][0]=z4; ah[1][0]=z4; }
    gemmW<4,1,8,2>(ah, hb, STRH, blob+OFF_HZ, lane, w);
    f4 zr[2];
    #pragma unroll
    for(int rt=0;rt<2;rt++)
      #pragma unroll
      for(int g=0;g<4;g++){
        float z = sigmoidf_(ax[rt][0][g] + ah[rt][0][g]);
        zr[rt][g]=z;
        un[(rt*16+a4*4+g)*STRH + permk(w*16+lc)] = f2bf(z*hFr[rt][g]);   // zh
      }
    __syncthreads();
    { f4 z4={0.f,0.f,0.f,0.f}; ah[0][0]=z4; ah[1][0]=z4; }
    gemmW<4,1,8,2>(ah, un, STRH, blob+OFF_HN, lane, w);
    #pragma unroll
    for(int rt=0;rt<2;rt++)
      #pragma unroll
      for(int g=0;g<4;g++){
        float nn = tanhf(ax[rt][1][g] + ah[rt][0][g]);
        float ho = hFr[rt][g];
        float hv = ho + DT_*(1.f-zr[rt][g])*(nn-ho);
        hFr[rt][g]=hv;
        hb[(rt*16+a4*4+g)*STRH + permk(w*16+lc)] = f2bf(hv);
      }
    __syncthreads();
  };

  // ---- Bayesian jump: merged-gate GEMMs (tiles {w, w+8, w+16} of 384-wide) ----
  auto jump = [&](int t){
    if(tid < 32){
      unsigned short v = inv[(size_t)t*B_ + base + tid];
      obsO[tid] = (v == 0xFFFFu) ? -1 : (int)v;
    }
    __syncthreads();
    { // gin + loss: thread -> (row = tid>>4, d in {2q,2q+1})
      int row = tid>>4, q = tid&15, d0 = q*2;
      int o = obsO[row];
      float xa[2]={0.f,0.f}, ma[2]={0.f,0.f};
      if(o>=0){
        const float2 xv = *(const float2*)(X + ((size_t)t*NO_+o)*D_ + d0);
        const float2 mv = *(const float2*)(M + ((size_t)t*NO_+o)*D_ + d0);
        xa[0]=xv.x; xa[1]=xv.y; ma[0]=mv.x; ma[1]=mv.y;
      }
      #pragma unroll
      for(int j=0;j<2;j++){
        int d = d0+j;
        float mean = pf32[row*PFSTR + d];
        float lv   = pf32[row*PFSTR + D_ + d];
        float sg = __expf(0.5f*lv);
        float er = (xa[j]-mean)/sg;
        if(ma[j]>0.f) lsum += 0.5f*(er*er + lv + TWO_LOGC);
        const float* wp  = sb + SB_WPREP + d*4*PREP_;
        const float* bpv = sb + SB_BPREP + d*PREP_;
        #pragma unroll
        for(int pr=0;pr<PREP_;pr++){
          float s = xa[j]*wp[pr] + mean*wp[PREP_+pr] + lv*wp[2*PREP_+pr] + er*wp[3*PREP_+pr] + bpv[pr];
          s = fmaxf(s,0.f);
          un[row*STRG + permk(d*PREP_+pr)] = f2bf((ma[j]>0.f)? s : 0.f);  // gin
        }
      }
    }
    __syncthreads();
    // gi = gin @ [wih_r|wih_z|wih_n] (+ biases); gh = h @ [whh_r|whh_z|whh_n]
    f4 gi[2][3];
    #pragma unroll
    for(int rt=0;rt<2;rt++){
      float br = sb[SB_BRZ + w*16+lc], bz = sb[SB_BRZ+128 + w*16+lc], bn = sb[SB_BIN + w*16+lc];
      f4 tr={br,br,br,br}, tz={bz,bz,bz,bz}, tn={bn,bn,bn,bn};
      gi[rt][0]=tr; gi[rt][1]=tz; gi[rt][2]=tn;
    }
    gemmW<10,3,24,2>(gi, un, STRG, blob+OFF_WIH, lane, w);
    f4 gh[2][3];
    #pragma unroll
    for(int rt=0;rt<2;rt++){
      float bhn = sb[SB_BHN + w*16+lc];
      f4 z4={0.f,0.f,0.f,0.f}, tn={bhn,bhn,bhn,bhn};
      gh[rt][0]=z4; gh[rt][1]=z4; gh[rt][2]=tn;
    }
    gemmW<4,3,24,2>(gh, hb, STRH, blob+OFF_WHH, lane, w);
    __syncthreads();   // all waves done reading hb/un before conditional hb writes
    #pragma unroll
    for(int rt=0;rt<2;rt++)
      #pragma unroll
      for(int g=0;g<4;g++){
        int row = rt*16+a4*4+g;
        float r = sigmoidf_(gi[rt][0][g] + gh[rt][0][g]);
        float z = sigmoidf_(gi[rt][1][g] + gh[rt][1][g]);
        float nn = tanhf(gi[rt][2][g] + r*gh[rt][2][g]);
        float hv = (1.f-z)*nn + z*hFr[rt][g];
        if(obsO[row]>=0){
          hFr[rt][g]=hv;
          hb[row*STRH + permk(w*16+lc)] = f2bf(hv);
        }
      }
    __syncthreads();
  };

  // ---- sequence ----
  pmodel();
  for(int t=0;t<NT_;t++){
    euler();
    pmodel();
    jump(t);
    pmodel();
  }
  for(int it=0;it<NPOST_;it++){
    euler();
    pmodel();
  }

  // ---- outputs ----
  #pragma unroll
  for(int rt=0;rt<2;rt++)
    #pragma unroll
    for(int g=0;g<4;g++)
      outH[(size_t)(base + rt*16+a4*4+g)*H_ + w*16+lc] = hFr[rt][g];
  #pragma unroll
  for(int g=0;g<4;g++)
    outP[(size_t)(base + prt*16+a4*4+g)*(2*D_) + pct*16+lc] = pFr[g];

  #pragma unroll
  for(int off=32;off>0;off>>=1) lsum += __shfl_down(lsum, off);
  if(lane==0) lred[w]=lsum;
  __syncthreads();
  if(tid==0){
    float s = 0.f;
    #pragma unroll
    for(int i=0;i<8;i++) s += lred[i];
    atomicAdd(outLoss, s);
  }
}

// ---------------- launcher ----------------
extern "C" void kernel_launch(void* const* d_in, const int* in_sizes, int n_in,
                              void* d_out, int out_size, void* d_ws, size_t ws_size,
                              hipStream_t stream){
  const float* X      = (const float*)d_in[0];
  const float* M      = (const float*)d_in[1];
  const int*   obs    = (const int*)  d_in[2];
  const float* cov    = (const float*)d_in[3];
  const float* cm_w1  = (const float*)d_in[4];
  const float* cm_b1  = (const float*)d_in[5];
  const float* cm_w2  = (const float*)d_in[6];
  const float* cm_b2  = (const float*)d_in[7];
  const float* p_w1   = (const float*)d_in[8];
  const float* p_b1   = (const float*)d_in[9];
  const float* p_w2   = (const float*)d_in[10];
  const float* p_b2   = (const float*)d_in[11];
  const float* xz_w   = (const float*)d_in[12];
  const float* xz_b   = (const float*)d_in[13];
  const float* hz_w   = (const float*)d_in[14];
  const float* xn_w   = (const float*)d_in[15];
  const float* xn_b   = (const float*)d_in[16];
  const float* hn_w   = (const float*)d_in[17];
  const float* w_ih   = (const float*)d_in[18];
  const float* w_hh   = (const float*)d_in[19];
  const float* b_ih   = (const float*)d_in[20];
  const float* b_hh   = (const float*)d_in[21];
  const float* w_prep = (const float*)d_in[22];
  const float* bprep  = (const float*)d_in[23];

  unsigned short* blob = (unsigned short*)d_ws;
  unsigned short* inv  = (unsigned short*)((char*)d_ws + INV_BYTE_OFF);
  float* outH = (float*)d_out;
  float* outP = outH + (size_t)B_*H_;
  float* outLoss = outP + (size_t)B_*2*D_;

  init_inv   <<<dim3((NT_*B_+255)/256), dim3(256), 0, stream>>>(inv, outLoss);
  scatter_inv<<<dim3((NT_*NO_+255)/256), dim3(256), 0, stream>>>(inv, obs);
  build_blobs<<<dim3(480,7), dim3(256), 0, stream>>>(p_w1,p_w2,xz_w,xn_w,hz_w,hn_w,w_ih,w_hh, blob);
  fused      <<<dim3(B_/32), dim3(512), 0, stream>>>(
      X, M, cov, cm_w1, cm_b1, cm_w2, cm_b2, p_b1, p_b2, xz_b, xn_b,
      b_ih, b_hh, w_prep, bprep, blob, inv, outH, outP, outLoss);
}